// Round 7
// baseline (307.024 us; speedup 1.0000x reference)
//
#include <hip/hip_runtime.h>

// ---------------- problem constants ----------------
#define LSEQ   16384        // H*W
#define BLROWS 65536        // B * L
#define DM     256          // d_model
#define DI     512          // d_inner
#define DXZ    1024         // 2 * d_inner

// GEMM tile
#define BM 128
#define BN 128
#define BK 64

typedef __attribute__((ext_vector_type(8))) short s16x8;
typedef __attribute__((ext_vector_type(4))) short s16x4;
typedef __attribute__((ext_vector_type(4))) float f32x4;

__device__ __forceinline__ float bf2f(unsigned short h) {
  union { unsigned u; float f; } c; c.u = ((unsigned)h) << 16; return c.f;
}
__device__ __forceinline__ unsigned short f2bf(float f) {
  union { float f; unsigned u; } c; c.f = f;
  unsigned u = c.u;
  return (unsigned short)((u + 0x7fffu + ((u >> 16) & 1u)) >> 16);
}

// ---------------- fp32 -> bf16 convert ----------------
__global__ __launch_bounds__(256)
void cvt_f32_bf16(const float* __restrict__ src, unsigned short* __restrict__ dst, int n4) {
  for (int i = blockIdx.x * blockDim.x + threadIdx.x; i < n4; i += gridDim.x * blockDim.x) {
    const float4 v = reinterpret_cast<const float4*>(src)[i];
    s16x4 o;
    o[0] = (short)f2bf(v.x);
    o[1] = (short)f2bf(v.y);
    o[2] = (short)f2bf(v.z);
    o[3] = (short)f2bf(v.w);
    reinterpret_cast<s16x4*>(dst)[i] = o;
  }
}

// ---------------- async global->LDS (16B per lane) ----------------
__device__ __forceinline__ void gload16(const void* g, void* l) {
  __builtin_amdgcn_global_load_lds((__attribute__((address_space(1))) void*)(g),
                                   (__attribute__((address_space(3))) void*)(l),
                                   16, 0, 0);
}

// swizzled byte offset for the epilogue conv tiles: row stride 128B,
// XOR of bits 4..6 with row&7 breaks the 128B bank period (G4).
__device__ __forceinline__ int xswz(int row, int byteInRow) {
  return row * 128 + (byteInRow ^ ((row & 7) << 4));
}

// ============================================================================
// Fused GEMM1 + depthwise causal conv(K=4) + bias + SiLU + gate.
//   A  = x_bf   [65536, 256]
//   Bw = win_bf [1024, 256]   (rows 0..511 = x-branch, 512..1023 = z-branch)
//   Y  = y_bf   [65536, 512]
// Block computes 128 rows x (64 x-cols + matching 64 z-cols), then applies
// conv+gate in LDS and writes y directly. grid = (512/64, 65536/128)
// ============================================================================
__global__ __launch_bounds__(256, 2)
void gemm1_conv(const unsigned short* __restrict__ A,
                const unsigned short* __restrict__ Bw,
                const float* __restrict__ cw,    // [512][4]
                const float* __restrict__ cb,    // [512]
                unsigned short* __restrict__ Y) {
  __shared__ unsigned short lds[2][BM * BK + BN * BK];   // 64 KB

  const int tid  = threadIdx.x;
  const int lane = tid & 63;
  const int wv   = tid >> 6;
  const int wr   = wv >> 1;         // 0..1 row-quadrant
  const int wc   = wv & 1;          // 0 -> x-cols, 1 -> z-cols
  const int m0   = blockIdx.y * BM;
  const int n0x  = blockIdx.x * 64; // x-channel base (0..448)

  const int srow = tid >> 3;        // 0..31
  const int scol = (tid & 7) * 8;   // 0..56

  f32x4 acc[4][4];
#pragma unroll
  for (int i = 0; i < 4; ++i)
#pragma unroll
    for (int j = 0; j < 4; ++j)
#pragma unroll
      for (int r = 0; r < 4; ++r) acc[i][j][r] = 0.f;

  auto stage = [&](int ks, int buf) {
    const unsigned short* Ag = A + (size_t)(m0 + srow) * DM + ks * BK + scol;
    unsigned short* lA = &lds[buf][0]       + tid * 8;
    unsigned short* lB = &lds[buf][BM * BK] + tid * 8;
#pragma unroll
    for (int i = 0; i < 4; ++i) {
      gload16(Ag + (size_t)(i * 32) * DM, lA + i * 2048);
      const int lr   = srow + i * 32;                    // local B row 0..127
      const int grow = (i < 2) ? (n0x + lr) : (448 + n0x + lr); // x rows / z rows
      gload16(Bw + (size_t)grow * DM + ks * BK + scol, lB + i * 2048);
    }
  };

  stage(0, 0);

  const int kSteps = DM / BK;   // 4
  for (int ks = 0; ks < kSteps; ++ks) {
    const int cur = ks & 1;
    __syncthreads();
    if (ks + 1 < kSteps) stage(ks + 1, cur ^ 1);

    const unsigned short* lA = &lds[cur][0];
    const unsigned short* lB = &lds[cur][BM * BK];
    const int lrow = lane & 15;
#pragma unroll
    for (int kk = 0; kk < BK; kk += 32) {
      const int lk = kk + ((lane >> 4) << 3);
      s16x8 af[4], bf[4];
#pragma unroll
      for (int i = 0; i < 4; ++i)
        af[i] = *(const s16x8*)(lA + (wr * 64 + i * 16 + lrow) * BK + lk);
#pragma unroll
      for (int j = 0; j < 4; ++j)
        bf[j] = *(const s16x8*)(lB + (wc * 64 + j * 16 + lrow) * BK + lk);
#pragma unroll
      for (int i = 0; i < 4; ++i)
#pragma unroll
        for (int j = 0; j < 4; ++j)
          acc[i][j] = __builtin_amdgcn_mfma_f32_16x16x32_bf16(af[i], bf[j], acc[i][j], 0, 0, 0);
    }
  }

  // ---------------- fused epilogue ----------------
  // LDS reuse: xt = [131][64] bf16 swizzled at byte 0 (rows 0..2 = halo),
  //            zt = [128][64] bf16 swizzled at byte 16768.
  __syncthreads();                      // all frag reads done; LDS free
  char* ldsb = (char*)&lds[0][0];
  const int r0 = (lane >> 4) * 4;
  const int c0 = lane & 15;

  if (wc == 0) {
#pragma unroll
    for (int i = 0; i < 4; ++i)
#pragma unroll
      for (int j = 0; j < 4; ++j)
#pragma unroll
        for (int r = 0; r < 4; ++r) {
          const int row = wr * 64 + i * 16 + r0 + r;     // 0..127
          const int col = j * 16 + c0;                   // 0..63
          *(unsigned short*)(ldsb + xswz(row + 3, col * 2)) = f2bf(acc[i][j][r]);
        }
  } else {
#pragma unroll
    for (int i = 0; i < 4; ++i)
#pragma unroll
      for (int j = 0; j < 4; ++j)
#pragma unroll
        for (int r = 0; r < 4; ++r) {
          const int row = wr * 64 + i * 16 + r0 + r;
          const int col = j * 16 + c0;
          *(unsigned short*)(ldsb + 16768 + xswz(row, col * 2)) = f2bf(acc[i][j][r]);
        }
  }

  // halo rows m0-3..m0-1 (x-branch), recomputed in fp32; zero at batch start
  if (tid < 192) {
    const int hi = tid >> 6;       // 0..2
    const int hc = tid & 63;       // 0..63
    float s = 0.f;
    if ((m0 & (LSEQ - 1)) != 0) {
      const unsigned short* xr = A  + (size_t)(m0 - 3 + hi) * DM;   // wave-uniform
      const unsigned short* wr_ = Bw + (size_t)(n0x + hc) * DM;
#pragma unroll
      for (int kk = 0; kk < DM; kk += 8) {
        const s16x8 xa = *(const s16x8*)(xr + kk);
        const s16x8 wa = *(const s16x8*)(wr_ + kk);
#pragma unroll
        for (int j = 0; j < 8; ++j)
          s += bf2f((unsigned short)xa[j]) * bf2f((unsigned short)wa[j]);
      }
    }
    *(unsigned short*)(ldsb + xswz(hi, hc * 2)) = f2bf(s);
  }
  __syncthreads();

  // conv + bias + silu*silu gate, write y
  const int rr2 = tid >> 1;              // 0..127
  const int cb2 = (tid & 1) * 32;        // 0 or 32
#pragma unroll
  for (int v = 0; v < 4; ++v) {
    const int c = cb2 + v * 8;
    const s16x8 t0 = *(const s16x8*)(ldsb + xswz(rr2 + 0, c * 2));
    const s16x8 t1 = *(const s16x8*)(ldsb + xswz(rr2 + 1, c * 2));
    const s16x8 t2 = *(const s16x8*)(ldsb + xswz(rr2 + 2, c * 2));
    const s16x8 t3 = *(const s16x8*)(ldsb + xswz(rr2 + 3, c * 2));
    const s16x8 zv = *(const s16x8*)(ldsb + 16768 + xswz(rr2, c * 2));
    s16x8 o;
#pragma unroll
    for (int j = 0; j < 8; ++j) {
      const int ch = n0x + c + j;                        // 0..511
      const float4 w4 = *(const float4*)(cw + (size_t)ch * 4);
      float a = cb[ch];
      a += w4.x * bf2f((unsigned short)t0[j]);
      a += w4.y * bf2f((unsigned short)t1[j]);
      a += w4.z * bf2f((unsigned short)t2[j]);
      a += w4.w * bf2f((unsigned short)t3[j]);
      const float su = a * __builtin_amdgcn_rcpf(1.f + __expf(-a));
      const float z  = bf2f((unsigned short)zv[j]);
      const float sz = z * __builtin_amdgcn_rcpf(1.f + __expf(-z));
      o[j] = (short)f2bf(4.f * su * sz);
    }
    *(s16x8*)(Y + (size_t)(m0 + rr2) * DI + n0x + c) = o;
  }
}

// ---------------- bf16 GEMM: C[M,N] = A[M,K] @ B[N,K]^T, fp32 out ----------
__global__ __launch_bounds__(256, 2)
void gemm_bt_f32(const unsigned short* __restrict__ A,
                 const unsigned short* __restrict__ B,
                 float* __restrict__ C,
                 int M, int N, int K) {
  __shared__ unsigned short lds[2][BM * BK + BN * BK];

  const int tid  = threadIdx.x;
  const int lane = tid & 63;
  const int wv   = tid >> 6;
  const int wr   = wv >> 1;
  const int wc   = wv & 1;
  const int m0   = blockIdx.y * BM;
  const int n0   = blockIdx.x * BN;

  const int srow = tid >> 3;
  const int scol = (tid & 7) * 8;

  const int kSteps = K / BK;

  f32x4 acc[4][4];
#pragma unroll
  for (int i = 0; i < 4; ++i)
#pragma unroll
    for (int j = 0; j < 4; ++j)
#pragma unroll
      for (int r = 0; r < 4; ++r) acc[i][j][r] = 0.f;

  auto stage = [&](int ks, int buf) {
    const unsigned short* Ag = A + (size_t)(m0 + srow) * K + ks * BK + scol;
    const unsigned short* Bg = B + (size_t)(n0 + srow) * K + ks * BK + scol;
    unsigned short* lA = &lds[buf][0]       + tid * 8;
    unsigned short* lB = &lds[buf][BM * BK] + tid * 8;
#pragma unroll
    for (int i = 0; i < 4; ++i) {
      gload16(Ag + (size_t)(i * 32) * K, lA + i * 2048);
      gload16(Bg + (size_t)(i * 32) * K, lB + i * 2048);
    }
  };

  stage(0, 0);

  for (int ks = 0; ks < kSteps; ++ks) {
    const int cur = ks & 1;
    __syncthreads();
    if (ks + 1 < kSteps) stage(ks + 1, cur ^ 1);

    const unsigned short* lA = &lds[cur][0];
    const unsigned short* lB = &lds[cur][BM * BK];
    const int lrow = lane & 15;
#pragma unroll
    for (int kk = 0; kk < BK; kk += 32) {
      const int lk = kk + ((lane >> 4) << 3);
      s16x8 af[4], bf[4];
#pragma unroll
      for (int i = 0; i < 4; ++i)
        af[i] = *(const s16x8*)(lA + (wr * 64 + i * 16 + lrow) * BK + lk);
#pragma unroll
      for (int j = 0; j < 4; ++j)
        bf[j] = *(const s16x8*)(lB + (wc * 64 + j * 16 + lrow) * BK + lk);
#pragma unroll
      for (int i = 0; i < 4; ++i)
#pragma unroll
        for (int j = 0; j < 4; ++j)
          acc[i][j] = __builtin_amdgcn_mfma_f32_16x16x32_bf16(af[i], bf[j], acc[i][j], 0, 0, 0);
    }
  }

  const int r0 = (lane >> 4) * 4;
  const int c0 = lane & 15;
#pragma unroll
  for (int i = 0; i < 4; ++i)
#pragma unroll
    for (int j = 0; j < 4; ++j) {
      const int rr = m0 + wr * 64 + i * 16 + r0;
      const int cc = n0 + wc * 64 + j * 16 + c0;
#pragma unroll
      for (int r = 0; r < 4; ++r)
        C[(size_t)(rr + r) * N + cc] = acc[i][j][r];
    }
}

// ---------------- launch ----------------
extern "C" void kernel_launch(void* const* d_in, const int* in_sizes, int n_in,
                              void* d_out, int out_size, void* d_ws, size_t ws_size,
                              hipStream_t stream) {
  const float* x      = (const float*)d_in[0];
  const float* W_in   = (const float*)d_in[1];
  const float* conv_w = (const float*)d_in[2];
  const float* conv_b = (const float*)d_in[3];
  const float* W_out  = (const float*)d_in[4];

  char* ws = (char*)d_ws;
  unsigned short* y_bf    = (unsigned short*)(ws);                  // 64 MiB
  unsigned short* x_bf    = (unsigned short*)(ws + (64ull << 20));  // 32 MiB
  unsigned short* win_bf  = (unsigned short*)(ws + (100ull << 20));
  unsigned short* wout_bf = (unsigned short*)(ws + (101ull << 20));

  // 1) convert inputs to bf16
  cvt_f32_bf16<<<2048, 256, 0, stream>>>(x,     x_bf,    (BLROWS * DM) / 4);
  cvt_f32_bf16<<<256,  256, 0, stream>>>(W_in,  win_bf,  (DXZ * DM) / 4);
  cvt_f32_bf16<<<128,  256, 0, stream>>>(W_out, wout_bf, (DM * DI) / 4);

  // 2) fused: y = 4*silu(conv(x@W_in_x^T))*silu(x@W_in_z^T)   (65536 x 512)
  gemm1_conv<<<dim3(DI / 64, BLROWS / BM), 256, 0, stream>>>(
      x_bf, win_bf, conv_w, conv_b, y_bf);

  // 3) out = y @ W_out^T (65536 x 256, K=512), fp32 out
  gemm_bt_f32<<<dim3(DM / BN, BLROWS / BM), 256, 0, stream>>>(
      y_bf, wout_bf, (float*)d_out, BLROWS, DM, DI);
}

// Round 8
// 268.303 us; speedup vs baseline: 1.1443x; 1.1443x over previous
//
#include <hip/hip_runtime.h>

// ---------------- problem constants ----------------
#define LSEQ   16384        // H*W
#define BLROWS 65536        // B * L
#define DM     256          // d_model
#define DI     512          // d_inner
#define DXZ    1024         // 2 * d_inner

// GEMM tile
#define BM 128
#define BN 128
#define BK 64

typedef __attribute__((ext_vector_type(8))) short s16x8;
typedef __attribute__((ext_vector_type(4))) short s16x4;
typedef __attribute__((ext_vector_type(4))) float f32x4;

__device__ __forceinline__ float bf2f(unsigned short h) {
  union { unsigned u; float f; } c; c.u = ((unsigned)h) << 16; return c.f;
}
__device__ __forceinline__ unsigned short f2bf(float f) {
  union { float f; unsigned u; } c; c.f = f;
  unsigned u = c.u;
  return (unsigned short)((u + 0x7fffu + ((u >> 16) & 1u)) >> 16);
}

// ---------------- fp32 -> bf16 convert ----------------
__global__ __launch_bounds__(256)
void cvt_f32_bf16(const float* __restrict__ src, unsigned short* __restrict__ dst, int n4) {
  for (int i = blockIdx.x * blockDim.x + threadIdx.x; i < n4; i += gridDim.x * blockDim.x) {
    const float4 v = reinterpret_cast<const float4*>(src)[i];
    s16x4 o;
    o[0] = (short)f2bf(v.x);
    o[1] = (short)f2bf(v.y);
    o[2] = (short)f2bf(v.z);
    o[3] = (short)f2bf(v.w);
    reinterpret_cast<s16x4*>(dst)[i] = o;
  }
}

// ---------------- async global->LDS (16B per lane) ----------------
__device__ __forceinline__ void gload16(const void* g, void* l) {
  __builtin_amdgcn_global_load_lds((__attribute__((address_space(1))) void*)(g),
                                   (__attribute__((address_space(3))) void*)(l),
                                   16, 0, 0);
}

// ============================================================================
// Fused GEMM1 + depthwise causal conv(K=4) + bias + SiLU + gate.
// Register-resident epilogue: each wave owns 64 rows x (32 x-ch + 32 z-ch),
// conv taps via in-lane regs + shfl(lane-16); seams via 1.5KB LDS patch.
//   A  = x_bf   [65536, 256]
//   Bw = win_bf [1024, 256]   (rows 0..511 = x-branch, 512..1023 = z-branch)
//   Y  = y_bf   [65536, 512]
// grid = (512/64, 65536/128)
// ============================================================================
__global__ __launch_bounds__(256, 2)
void gemm1_conv(const unsigned short* __restrict__ A,
                const unsigned short* __restrict__ Bw,
                const float* __restrict__ cw,    // [512][4]
                const float* __restrict__ cb,    // [512]
                unsigned short* __restrict__ Y) {
  __shared__ unsigned short lds[2][BM * BK + BN * BK];   // 64 KB staging
  __shared__ float patch[2][3][64];                       // seam rows: [0]=block halo, [1]=rows 61..63

  const int tid  = threadIdx.x;
  const int lane = tid & 63;
  const int w    = tid >> 6;
  const int wr2  = w >> 1;          // 0..1 : row half (64 rows)
  const int wcol = w & 1;           // 0..1 : channel half (32 ch)
  const int g    = lane >> 4;       // quarter-group
  const int c0   = lane & 15;
  const int m0   = blockIdx.y * BM;
  const int n0x  = blockIdx.x * 64; // x-channel base (0..448)

  const int srow = tid >> 3;        // 0..31
  const int scol = (tid & 7) * 8;   // 0..56

  f32x4 ax[4][2], az[4][2];
#pragma unroll
  for (int i = 0; i < 4; ++i)
#pragma unroll
    for (int j = 0; j < 2; ++j)
#pragma unroll
      for (int r = 0; r < 4; ++r) { ax[i][j][r] = 0.f; az[i][j][r] = 0.f; }

  auto stage = [&](int ks, int buf) {
    const unsigned short* Ag = A + (size_t)(m0 + srow) * DM + ks * BK + scol;
    unsigned short* lA = &lds[buf][0]       + tid * 8;
    unsigned short* lB = &lds[buf][BM * BK] + tid * 8;
#pragma unroll
    for (int i = 0; i < 4; ++i) {
      gload16(Ag + (size_t)(i * 32) * DM, lA + i * 2048);
      const int lr   = srow + i * 32;                           // local B row 0..127
      const int grow = (i < 2) ? (n0x + lr) : (448 + n0x + lr); // x rows / z rows
      gload16(Bw + (size_t)grow * DM + ks * BK + scol, lB + i * 2048);
    }
  };

  stage(0, 0);

  const int kSteps = DM / BK;   // 4
  for (int ks = 0; ks < kSteps; ++ks) {
    const int cur = ks & 1;
    __syncthreads();
    if (ks + 1 < kSteps) stage(ks + 1, cur ^ 1);

    const unsigned short* lA = &lds[cur][0];
    const unsigned short* lB = &lds[cur][BM * BK];
    const int lrow = lane & 15;
#pragma unroll
    for (int kk = 0; kk < BK; kk += 32) {
      const int lk = kk + ((lane >> 4) << 3);
      s16x8 af[4], bx[2], bz[2];
#pragma unroll
      for (int i = 0; i < 4; ++i)
        af[i] = *(const s16x8*)(lA + (wr2 * 64 + i * 16 + lrow) * BK + lk);
#pragma unroll
      for (int j = 0; j < 2; ++j) {
        bx[j] = *(const s16x8*)(lB + (wcol * 32 + j * 16 + lrow) * BK + lk);
        bz[j] = *(const s16x8*)(lB + (64 + wcol * 32 + j * 16 + lrow) * BK + lk);
      }
#pragma unroll
      for (int i = 0; i < 4; ++i)
#pragma unroll
        for (int j = 0; j < 2; ++j) {
          ax[i][j] = __builtin_amdgcn_mfma_f32_16x16x32_bf16(af[i], bx[j], ax[i][j], 0, 0, 0);
          az[i][j] = __builtin_amdgcn_mfma_f32_16x16x32_bf16(af[i], bz[j], az[i][j], 0, 0, 0);
        }
    }
  }

  // ---------------- register-resident epilogue ----------------
  // Frag layout (verified r4/r7): ch = wcol*32 + j*16 + c0 ; m_local = wr2*64 + i*16 + g*4 + r.
  // (a) wave-boundary seam: wr2==0 waves' rows 61..63 -> patch[1]
  if (wr2 == 0 && g == 3) {
#pragma unroll
    for (int j = 0; j < 2; ++j) {
      const int chl = wcol * 32 + j * 16 + c0;
      patch[1][0][chl] = ax[3][j][1];   // row 61
      patch[1][1][chl] = ax[3][j][2];   // row 62
      patch[1][2][chl] = ax[3][j][3];   // row 63
    }
  }
  // (b) block halo rows m0-3..m0-1 (x-branch pre-activation), fp32 recompute
  if (tid < 192) {
    const int hi = tid >> 6;       // 0..2
    const int hc = tid & 63;       // 0..63
    float s = 0.f;
    if ((m0 & (LSEQ - 1)) != 0) {
      const unsigned short* xr  = A  + (size_t)(m0 - 3 + hi) * DM;
      const unsigned short* wr_ = Bw + (size_t)(n0x + hc) * DM;
#pragma unroll
      for (int kk = 0; kk < DM; kk += 8) {
        const s16x8 xa = *(const s16x8*)(xr + kk);
        const s16x8 wa = *(const s16x8*)(wr_ + kk);
#pragma unroll
        for (int jj = 0; jj < 8; ++jj)
          s += bf2f((unsigned short)xa[jj]) * bf2f((unsigned short)wa[jj]);
      }
    }
    patch[0][hi][hc] = s;
  }
  __syncthreads();

  // (c) conv + bias + silu*silu gate + scattered bf16 stores
  const int src = (lane - 16) & 63;
#pragma unroll
  for (int j = 0; j < 2; ++j) {
    const int chl = wcol * 32 + j * 16 + c0;
    const int ch  = n0x + chl;
    const float4 w4 = *(const float4*)(cw + (size_t)ch * 4);
    const float cbv = cb[ch];
#pragma unroll
    for (int i = 0; i < 4; ++i) {
      const f32x4 curf = ax[i][j];
      const f32x4 prvf = (i > 0) ? ax[(i > 0 ? i - 1 : 0)][j] : ax[0][j];
      // g==3 lanes serve g==0 dests of the NEXT 16-row frag -> send prev-frag top rows
      const float s1 = (g == 3) ? prvf[1] : curf[1];
      const float s2 = (g == 3) ? prvf[2] : curf[2];
      const float s3 = (g == 3) ? prvf[3] : curf[3];
      float vm3 = __shfl(s1, src);
      float vm2 = __shfl(s2, src);
      float vm1 = __shfl(s3, src);
      if (i == 0 && g == 0) {        // seam: wave boundary (wr2=1) or block halo (wr2=0)
        vm3 = patch[wr2][0][chl];
        vm2 = patch[wr2][1][chl];
        vm1 = patch[wr2][2][chl];
      }
      const float vv[7] = {vm3, vm2, vm1, curf[0], curf[1], curf[2], curf[3]};
      const int mbase = m0 + wr2 * 64 + i * 16 + g * 4;
#pragma unroll
      for (int r = 0; r < 4; ++r) {
        float a = cbv + w4.x * vv[r] + w4.y * vv[r + 1] + w4.z * vv[r + 2] + w4.w * vv[r + 3];
        const float su = a * __builtin_amdgcn_rcpf(1.f + __expf(-a));
        const float z  = az[i][j][r];
        const float sz = z * __builtin_amdgcn_rcpf(1.f + __expf(-z));
        Y[(size_t)(mbase + r) * DI + ch] = f2bf(4.f * su * sz);
      }
    }
  }
}

// ---------------- bf16 GEMM: C[M,N] = A[M,K] @ B[N,K]^T, fp32 out ----------
__global__ __launch_bounds__(256, 2)
void gemm_bt_f32(const unsigned short* __restrict__ A,
                 const unsigned short* __restrict__ B,
                 float* __restrict__ C,
                 int M, int N, int K) {
  __shared__ unsigned short lds[2][BM * BK + BN * BK];

  const int tid  = threadIdx.x;
  const int lane = tid & 63;
  const int wv   = tid >> 6;
  const int wr   = wv >> 1;
  const int wc   = wv & 1;
  const int m0   = blockIdx.y * BM;
  const int n0   = blockIdx.x * BN;

  const int srow = tid >> 3;
  const int scol = (tid & 7) * 8;

  const int kSteps = K / BK;

  f32x4 acc[4][4];
#pragma unroll
  for (int i = 0; i < 4; ++i)
#pragma unroll
    for (int j = 0; j < 4; ++j)
#pragma unroll
      for (int r = 0; r < 4; ++r) acc[i][j][r] = 0.f;

  auto stage = [&](int ks, int buf) {
    const unsigned short* Ag = A + (size_t)(m0 + srow) * K + ks * BK + scol;
    const unsigned short* Bg = B + (size_t)(n0 + srow) * K + ks * BK + scol;
    unsigned short* lA = &lds[buf][0]       + tid * 8;
    unsigned short* lB = &lds[buf][BM * BK] + tid * 8;
#pragma unroll
    for (int i = 0; i < 4; ++i) {
      gload16(Ag + (size_t)(i * 32) * K, lA + i * 2048);
      gload16(Bg + (size_t)(i * 32) * K, lB + i * 2048);
    }
  };

  stage(0, 0);

  for (int ks = 0; ks < kSteps; ++ks) {
    const int cur = ks & 1;
    __syncthreads();
    if (ks + 1 < kSteps) stage(ks + 1, cur ^ 1);

    const unsigned short* lA = &lds[cur][0];
    const unsigned short* lB = &lds[cur][BM * BK];
    const int lrow = lane & 15;
#pragma unroll
    for (int kk = 0; kk < BK; kk += 32) {
      const int lk = kk + ((lane >> 4) << 3);
      s16x8 af[4], bf[4];
#pragma unroll
      for (int i = 0; i < 4; ++i)
        af[i] = *(const s16x8*)(lA + (wr * 64 + i * 16 + lrow) * BK + lk);
#pragma unroll
      for (int j = 0; j < 4; ++j)
        bf[j] = *(const s16x8*)(lB + (wc * 64 + j * 16 + lrow) * BK + lk);
#pragma unroll
      for (int i = 0; i < 4; ++i)
#pragma unroll
        for (int j = 0; j < 4; ++j)
          acc[i][j] = __builtin_amdgcn_mfma_f32_16x16x32_bf16(af[i], bf[j], acc[i][j], 0, 0, 0);
    }
  }

  const int r0 = (lane >> 4) * 4;
  const int c0 = lane & 15;
#pragma unroll
  for (int i = 0; i < 4; ++i)
#pragma unroll
    for (int j = 0; j < 4; ++j) {
      const int rr = m0 + wr * 64 + i * 16 + r0;
      const int cc = n0 + wc * 64 + j * 16 + c0;
#pragma unroll
      for (int r = 0; r < 4; ++r)
        C[(size_t)(rr + r) * N + cc] = acc[i][j][r];
    }
}

// ---------------- launch ----------------
extern "C" void kernel_launch(void* const* d_in, const int* in_sizes, int n_in,
                              void* d_out, int out_size, void* d_ws, size_t ws_size,
                              hipStream_t stream) {
  const float* x      = (const float*)d_in[0];
  const float* W_in   = (const float*)d_in[1];
  const float* conv_w = (const float*)d_in[2];
  const float* conv_b = (const float*)d_in[3];
  const float* W_out  = (const float*)d_in[4];

  char* ws = (char*)d_ws;
  unsigned short* y_bf    = (unsigned short*)(ws);                  // 64 MiB
  unsigned short* x_bf    = (unsigned short*)(ws + (64ull << 20));  // 32 MiB
  unsigned short* win_bf  = (unsigned short*)(ws + (100ull << 20));
  unsigned short* wout_bf = (unsigned short*)(ws + (101ull << 20));

  // 1) convert inputs to bf16
  cvt_f32_bf16<<<2048, 256, 0, stream>>>(x,     x_bf,    (BLROWS * DM) / 4);
  cvt_f32_bf16<<<256,  256, 0, stream>>>(W_in,  win_bf,  (DXZ * DM) / 4);
  cvt_f32_bf16<<<128,  256, 0, stream>>>(W_out, wout_bf, (DM * DI) / 4);

  // 2) fused: y = 4*silu(conv(x@W_in_x^T))*silu(x@W_in_z^T)   (65536 x 512)
  gemm1_conv<<<dim3(DI / 64, BLROWS / BM), 256, 0, stream>>>(
      x_bf, win_bf, conv_w, conv_b, y_bf);

  // 3) out = y @ W_out^T (65536 x 256, K=512), fp32 out
  gemm_bt_f32<<<dim3(DM / BN, BLROWS / BM), 256, 0, stream>>>(
      y_bf, wout_bf, (float*)d_out, BLROWS, DM, DI);
}

// Round 9
// 265.526 us; speedup vs baseline: 1.1563x; 1.0105x over previous
//
#include <hip/hip_runtime.h>

// ---------------- problem constants ----------------
#define LSEQ   16384        // H*W
#define BLROWS 65536        // B * L
#define DM     256          // d_model
#define DI     512          // d_inner
#define DXZ    1024         // 2 * d_inner

// GEMM tile
#define BM 128
#define BN 128
#define BK 32               // r9: 64->32, halves LDS -> 4-5 blocks/CU (occupancy fix)

typedef __attribute__((ext_vector_type(8))) short s16x8;
typedef __attribute__((ext_vector_type(4))) short s16x4;
typedef __attribute__((ext_vector_type(4))) float f32x4;

__device__ __forceinline__ float bf2f(unsigned short h) {
  union { unsigned u; float f; } c; c.u = ((unsigned)h) << 16; return c.f;
}
__device__ __forceinline__ unsigned short f2bf(float f) {
  union { float f; unsigned u; } c; c.f = f;
  unsigned u = c.u;
  return (unsigned short)((u + 0x7fffu + ((u >> 16) & 1u)) >> 16);
}

// ---------------- fp32 -> bf16 convert ----------------
__global__ __launch_bounds__(256)
void cvt_f32_bf16(const float* __restrict__ src, unsigned short* __restrict__ dst, int n4) {
  for (int i = blockIdx.x * blockDim.x + threadIdx.x; i < n4; i += gridDim.x * blockDim.x) {
    const float4 v = reinterpret_cast<const float4*>(src)[i];
    s16x4 o;
    o[0] = (short)f2bf(v.x);
    o[1] = (short)f2bf(v.y);
    o[2] = (short)f2bf(v.z);
    o[3] = (short)f2bf(v.w);
    reinterpret_cast<s16x4*>(dst)[i] = o;
  }
}

// ---------------- async global->LDS (16B per lane) ----------------
__device__ __forceinline__ void gload16(const void* g, void* l) {
  __builtin_amdgcn_global_load_lds((__attribute__((address_space(1))) void*)(g),
                                   (__attribute__((address_space(3))) void*)(l),
                                   16, 0, 0);
}

// ============================================================================
// Fused GEMM1 + depthwise causal conv(K=4) + bias + SiLU + gate.
// Register-resident epilogue: each wave owns 64 rows x (32 x-ch + 32 z-ch),
// conv taps via in-lane regs + shfl(lane-16); seams via 1.5KB LDS patch.
//   A  = x_bf   [65536, 256]
//   Bw = win_bf [1024, 256]   (rows 0..511 = x-branch, 512..1023 = z-branch)
//   Y  = y_bf   [65536, 512]
// grid = (512/64, 65536/128); LDS 32KB staging + 1.5KB patch -> 4 blocks/CU
// ============================================================================
__global__ __launch_bounds__(256, 4)
void gemm1_conv(const unsigned short* __restrict__ A,
                const unsigned short* __restrict__ Bw,
                const float* __restrict__ cw,    // [512][4]
                const float* __restrict__ cb,    // [512]
                unsigned short* __restrict__ Y) {
  __shared__ unsigned short lds[2][BM * BK + BN * BK];   // 32 KB staging
  __shared__ float patch[2][3][64];                       // seam rows

  const int tid  = threadIdx.x;
  const int lane = tid & 63;
  const int w    = tid >> 6;
  const int wr2  = w >> 1;          // 0..1 : row half (64 rows)
  const int wcol = w & 1;           // 0..1 : channel half (32 ch)
  const int g    = lane >> 4;       // quarter-group
  const int c0   = lane & 15;
  const int m0   = blockIdx.y * BM;
  const int n0x  = blockIdx.x * 64; // x-channel base (0..448)

  const int srow = tid >> 2;        // 0..63
  const int scol = (tid & 3) * 8;   // 0,8,16,24

  f32x4 ax[4][2], az[4][2];
#pragma unroll
  for (int i = 0; i < 4; ++i)
#pragma unroll
    for (int j = 0; j < 2; ++j)
#pragma unroll
      for (int r = 0; r < 4; ++r) { ax[i][j][r] = 0.f; az[i][j][r] = 0.f; }

  auto stage = [&](int ks, int buf) {
    const unsigned short* Ag = A + (size_t)(m0 + srow) * DM + ks * BK + scol;
    unsigned short* lA = &lds[buf][0]       + tid * 8;
    unsigned short* lB = &lds[buf][BM * BK] + tid * 8;
#pragma unroll
    for (int i = 0; i < 2; ++i) {
      gload16(Ag + (size_t)(i * 64) * DM, lA + i * 2048);
      const int lr   = srow + i * 64;                           // local B row 0..127
      const int grow = (i == 0) ? (n0x + lr) : (448 + n0x + lr); // x rows / z rows
      gload16(Bw + (size_t)grow * DM + ks * BK + scol, lB + i * 2048);
    }
  };

  stage(0, 0);

  const int kSteps = DM / BK;   // 8
  for (int ks = 0; ks < kSteps; ++ks) {
    const int cur = ks & 1;
    __syncthreads();
    if (ks + 1 < kSteps) stage(ks + 1, cur ^ 1);

    const unsigned short* lA = &lds[cur][0];
    const unsigned short* lB = &lds[cur][BM * BK];
    const int lrow = lane & 15;
    const int lk   = g * 8;
    s16x8 af[4], bx[2], bz[2];
#pragma unroll
    for (int i = 0; i < 4; ++i)
      af[i] = *(const s16x8*)(lA + (wr2 * 64 + i * 16 + lrow) * BK + lk);
#pragma unroll
    for (int j = 0; j < 2; ++j) {
      bx[j] = *(const s16x8*)(lB + (wcol * 32 + j * 16 + lrow) * BK + lk);
      bz[j] = *(const s16x8*)(lB + (64 + wcol * 32 + j * 16 + lrow) * BK + lk);
    }
#pragma unroll
    for (int i = 0; i < 4; ++i)
#pragma unroll
      for (int j = 0; j < 2; ++j) {
        ax[i][j] = __builtin_amdgcn_mfma_f32_16x16x32_bf16(af[i], bx[j], ax[i][j], 0, 0, 0);
        az[i][j] = __builtin_amdgcn_mfma_f32_16x16x32_bf16(af[i], bz[j], az[i][j], 0, 0, 0);
      }
  }

  // ---------------- register-resident epilogue ----------------
  // Frag layout: ch = wcol*32 + j*16 + c0 ; m_local = wr2*64 + i*16 + g*4 + r.
  if (wr2 == 0 && g == 3) {
#pragma unroll
    for (int j = 0; j < 2; ++j) {
      const int chl = wcol * 32 + j * 16 + c0;
      patch[1][0][chl] = ax[3][j][1];   // row 61
      patch[1][1][chl] = ax[3][j][2];   // row 62
      patch[1][2][chl] = ax[3][j][3];   // row 63
    }
  }
  // block halo rows m0-3..m0-1 (x-branch pre-activation), fp32 recompute
  if (tid < 192) {
    const int hi = tid >> 6;       // 0..2
    const int hc = tid & 63;       // 0..63
    float s = 0.f;
    if ((m0 & (LSEQ - 1)) != 0) {
      const unsigned short* xr  = A  + (size_t)(m0 - 3 + hi) * DM;
      const unsigned short* wr_ = Bw + (size_t)(n0x + hc) * DM;
#pragma unroll
      for (int kk = 0; kk < DM; kk += 8) {
        const s16x8 xa = *(const s16x8*)(xr + kk);
        const s16x8 wa = *(const s16x8*)(wr_ + kk);
#pragma unroll
        for (int jj = 0; jj < 8; ++jj)
          s += bf2f((unsigned short)xa[jj]) * bf2f((unsigned short)wa[jj]);
      }
    }
    patch[0][hi][hc] = s;
  }
  __syncthreads();

  // conv + bias + silu*silu gate + bf16 stores
  const int src = (lane - 16) & 63;
#pragma unroll
  for (int j = 0; j < 2; ++j) {
    const int chl = wcol * 32 + j * 16 + c0;
    const int ch  = n0x + chl;
    const float4 w4 = *(const float4*)(cw + (size_t)ch * 4);
    const float cbv = cb[ch];
#pragma unroll
    for (int i = 0; i < 4; ++i) {
      const f32x4 curf = ax[i][j];
      const f32x4 prvf = (i > 0) ? ax[(i > 0 ? i - 1 : 0)][j] : ax[0][j];
      const float s1 = (g == 3) ? prvf[1] : curf[1];
      const float s2 = (g == 3) ? prvf[2] : curf[2];
      const float s3 = (g == 3) ? prvf[3] : curf[3];
      float vm3 = __shfl(s1, src);
      float vm2 = __shfl(s2, src);
      float vm1 = __shfl(s3, src);
      if (i == 0 && g == 0) {
        vm3 = patch[wr2][0][chl];
        vm2 = patch[wr2][1][chl];
        vm1 = patch[wr2][2][chl];
      }
      const float vv[7] = {vm3, vm2, vm1, curf[0], curf[1], curf[2], curf[3]};
      const int mbase = m0 + wr2 * 64 + i * 16 + g * 4;
#pragma unroll
      for (int r = 0; r < 4; ++r) {
        float a = cbv + w4.x * vv[r] + w4.y * vv[r + 1] + w4.z * vv[r + 2] + w4.w * vv[r + 3];
        const float su = a * __builtin_amdgcn_rcpf(1.f + __expf(-a));
        const float z  = az[i][j][r];
        const float sz = z * __builtin_amdgcn_rcpf(1.f + __expf(-z));
        Y[(size_t)(mbase + r) * DI + ch] = f2bf(4.f * su * sz);
      }
    }
  }
}

// ---------------- bf16 GEMM: C[M,N] = A[M,K] @ B[N,K]^T, fp32 out ----------
__global__ __launch_bounds__(256, 4)
void gemm_bt_f32(const unsigned short* __restrict__ A,
                 const unsigned short* __restrict__ B,
                 float* __restrict__ C,
                 int M, int N, int K) {
  __shared__ unsigned short lds[2][BM * BK + BN * BK];   // 32 KB

  const int tid  = threadIdx.x;
  const int lane = tid & 63;
  const int wv   = tid >> 6;
  const int wr   = wv >> 1;
  const int wc   = wv & 1;
  const int m0   = blockIdx.y * BM;
  const int n0   = blockIdx.x * BN;

  const int srow = tid >> 2;        // 0..63
  const int scol = (tid & 3) * 8;   // 0,8,16,24

  const int kSteps = K / BK;

  f32x4 acc[4][4];
#pragma unroll
  for (int i = 0; i < 4; ++i)
#pragma unroll
    for (int j = 0; j < 4; ++j)
#pragma unroll
      for (int r = 0; r < 4; ++r) acc[i][j][r] = 0.f;

  auto stage = [&](int ks, int buf) {
    const unsigned short* Ag = A + (size_t)(m0 + srow) * K + ks * BK + scol;
    const unsigned short* Bg = B + (size_t)(n0 + srow) * K + ks * BK + scol;
    unsigned short* lA = &lds[buf][0]       + tid * 8;
    unsigned short* lB = &lds[buf][BM * BK] + tid * 8;
#pragma unroll
    for (int i = 0; i < 2; ++i) {
      gload16(Ag + (size_t)(i * 64) * K, lA + i * 2048);
      gload16(Bg + (size_t)(i * 64) * K, lB + i * 2048);
    }
  };

  stage(0, 0);

  for (int ks = 0; ks < kSteps; ++ks) {
    const int cur = ks & 1;
    __syncthreads();
    if (ks + 1 < kSteps) stage(ks + 1, cur ^ 1);

    const unsigned short* lA = &lds[cur][0];
    const unsigned short* lB = &lds[cur][BM * BK];
    const int lrow = lane & 15;
    const int lk   = (lane >> 4) * 8;
    s16x8 af[4], bf[4];
#pragma unroll
    for (int i = 0; i < 4; ++i)
      af[i] = *(const s16x8*)(lA + (wr * 64 + i * 16 + lrow) * BK + lk);
#pragma unroll
    for (int j = 0; j < 4; ++j)
      bf[j] = *(const s16x8*)(lB + (wc * 64 + j * 16 + lrow) * BK + lk);
#pragma unroll
    for (int i = 0; i < 4; ++i)
#pragma unroll
      for (int j = 0; j < 4; ++j)
        acc[i][j] = __builtin_amdgcn_mfma_f32_16x16x32_bf16(af[i], bf[j], acc[i][j], 0, 0, 0);
  }

  const int r0 = (lane >> 4) * 4;
  const int c0 = lane & 15;
#pragma unroll
  for (int i = 0; i < 4; ++i)
#pragma unroll
    for (int j = 0; j < 4; ++j) {
      const int rr = m0 + wr * 64 + i * 16 + r0;
      const int cc = n0 + wc * 64 + j * 16 + c0;
#pragma unroll
      for (int r = 0; r < 4; ++r)
        C[(size_t)(rr + r) * N + cc] = acc[i][j][r];
    }
}

// ---------------- launch ----------------
extern "C" void kernel_launch(void* const* d_in, const int* in_sizes, int n_in,
                              void* d_out, int out_size, void* d_ws, size_t ws_size,
                              hipStream_t stream) {
  const float* x      = (const float*)d_in[0];
  const float* W_in   = (const float*)d_in[1];
  const float* conv_w = (const float*)d_in[2];
  const float* conv_b = (const float*)d_in[3];
  const float* W_out  = (const float*)d_in[4];

  char* ws = (char*)d_ws;
  unsigned short* y_bf    = (unsigned short*)(ws);                  // 64 MiB
  unsigned short* x_bf    = (unsigned short*)(ws + (64ull << 20));  // 32 MiB
  unsigned short* win_bf  = (unsigned short*)(ws + (100ull << 20));
  unsigned short* wout_bf = (unsigned short*)(ws + (101ull << 20));

  // 1) convert inputs to bf16
  cvt_f32_bf16<<<2048, 256, 0, stream>>>(x,     x_bf,    (BLROWS * DM) / 4);
  cvt_f32_bf16<<<256,  256, 0, stream>>>(W_in,  win_bf,  (DXZ * DM) / 4);
  cvt_f32_bf16<<<128,  256, 0, stream>>>(W_out, wout_bf, (DM * DI) / 4);

  // 2) fused: y = 4*silu(conv(x@W_in_x^T))*silu(x@W_in_z^T)   (65536 x 512)
  gemm1_conv<<<dim3(DI / 64, BLROWS / BM), 256, 0, stream>>>(
      x_bf, win_bf, conv_w, conv_b, y_bf);

  // 3) out = y @ W_out^T (65536 x 256, K=512), fp32 out
  gemm_bt_f32<<<dim3(DM / BN, BLROWS / BM), 256, 0, stream>>>(
      y_bf, wout_bf, (float*)d_out, BLROWS, DM, DI);
}